// Round 6
// baseline (142.954 us; speedup 1.0000x reference)
//
#include <hip/hip_runtime.h>
#include <hip/hip_bf16.h>

typedef _Float16 half8 __attribute__((ext_vector_type(8)));
typedef _Float16 half4 __attribute__((ext_vector_type(4)));
typedef float floatx4 __attribute__((ext_vector_type(4)));

#define PD 768   // projection dim (N)
#define KE 768   // effective K (16*16*3)
#define NB 64

// class row-bases (rows grouped by class; all class sizes are multiples of 64)
__device__ __forceinline__ int cls_row_base(int cls) {
  return (cls == 0) ? 0 : (cls == 1) ? 64 : (cls == 2) ? 832 : (cls == 3) ? 896
       : (cls == 4) ? 1664 : (cls == 5) ? 10880 : (cls == 6) ? 11648
       : (cls == 7) ? 11712 : 12480;
}

__device__ __forceinline__ void gl_lds16(const _Float16* g, _Float16* l) {
  __builtin_amdgcn_global_load_lds(
      (const __attribute__((address_space(1))) unsigned int*)g,
      (__attribute__((address_space(3))) unsigned int*)l, 16, 0, 0);
}

// ---------------------------------------------------------------------------
// Kernel 1 (v2): fold masked channel-groups into 9 per-class weights, f16,
// layout Weff[cls][d][kk]. 4 pixels (12 kk) x 64 d per block -> 768 blocks
// (fills 256 CUs, 16 KB LDS vs old 65 KB / 192 blocks).
// ---------------------------------------------------------------------------
__global__ __launch_bounds__(256) void prep_weights(
    const float* __restrict__ W, _Float16* __restrict__ Weff) {
  __shared__ float Wl[60][68];      // 60 W-rows (4 px x 15 ch) x 64 d
  const int t  = threadIdx.x;
  const int ck = blockIdx.x & 63;   // kk-chunk (12 kk = 4 pixels)
  const int cd = blockIdx.x >> 6;   // d-chunk (64)
  const int p0 = ck * 4;
  const int d0 = cd * 64;
  for (int c = t; c < 960; c += 256) {   // 60 rows * 16 float4
    int row = c >> 4, off = (c & 15) * 4;
    *(floatx4*)&Wl[row][off] =
        *(const floatx4*)&W[(size_t)(p0 * 15 + row) * PD + d0 + off];
  }
  __syncthreads();
  if (t < 192) {                    // 64 d x 3 kk-quads
    int d = t / 3, q = t - (t / 3) * 3;
    float vout[9][4];
#pragma unroll
    for (int s = 0; s < 4; ++s) {
      int kl = q * 4 + s;           // 0..11
      int pl = kl / 3, cc = kl - pl * 3;
      int pix = p0 + pl;
      int ph = pix >> 4, pw = pix & 15;
      int rb = pl * 15 + cc;
      float w0 = Wl[rb][d],     w1 = Wl[rb + 3][d], w2 = Wl[rb + 6][d],
            w3 = Wl[rb + 9][d], w4 = Wl[rb + 12][d];
      float hlt[3] = {1.f, 1.f, (ph < 8) ? 1.f : 0.f};
      float hge[3] = {(ph >= 8) ? 1.f : 0.f, 1.f, 1.f};
      float wlt[3] = {1.f, 1.f, (pw < 8) ? 1.f : 0.f};
      float wge[3] = {(pw >= 8) ? 1.f : 0.f, 1.f, 1.f};
#pragma unroll
      for (int rh = 0; rh < 3; ++rh)
#pragma unroll
        for (int rw = 0; rw < 3; ++rw)
          vout[rh * 3 + rw][s] = w0 + hlt[rh] * wlt[rw] * w1
              + hge[rh] * wlt[rw] * w2 + hlt[rh] * wge[rw] * w3
              + hge[rh] * wge[rw] * w4;
    }
#pragma unroll
    for (int cls = 0; cls < 9; ++cls) {
      half4 h;
      h.x = (_Float16)vout[cls][0]; h.y = (_Float16)vout[cls][1];
      h.z = (_Float16)vout[cls][2]; h.w = (_Float16)vout[cls][3];
      *(half4*)&Weff[((size_t)cls * PD + d0 + d) * KE + ck * 12 + q * 4] = h;
    }
  }
}

// ---------------------------------------------------------------------------
// Kernel 2: im2col + f32->f16: A[12544][768], rows class-grouped.
// ---------------------------------------------------------------------------
__global__ __launch_bounds__(256) void prep_imcol(
    const float* __restrict__ img, _Float16* __restrict__ Ap) {
  const int total = NB * 224 * 84;          // 1,204,224 8-float items
  for (int id = blockIdx.x * 256 + threadIdx.x; id < total; id += 2048 * 256) {
    int b   = id / 18816;
    int rem = id - b * 18816;
    int h   = rem / 84;
    int c8  = rem - h * 84;
    int gw  = c8 / 6;
    int j8  = c8 - gw * 6;
    int gh  = h >> 4, ph = h & 15;
    int rh  = (gh == 0) ? 0 : ((gh >= 13) ? 2 : 1);
    int rw  = (gw == 0) ? 0 : ((gw >= 13) ? 2 : 1);
    int gh0 = (rh == 1) ? 1 : ((rh == 2) ? 13 : 0);
    int gw0 = (rw == 1) ? 1 : ((rw == 2) ? 13 : 0);
    int nh  = (rh == 1) ? 12 : 1;
    int nw  = (rw == 1) ? 12 : 1;
    int cls = rh * 3 + rw;
    int r   = cls_row_base(cls) + (b * nh + (gh - gh0)) * nw + (gw - gw0);
    const float* src = img + (size_t)(b * 224 + h) * 672 + c8 * 8;
    floatx4 v0 = *(const floatx4*)src;
    floatx4 v1 = *(const floatx4*)(src + 4);
    half8 o;
    o[0] = (_Float16)v0.x; o[1] = (_Float16)v0.y;
    o[2] = (_Float16)v0.z; o[3] = (_Float16)v0.w;
    o[4] = (_Float16)v1.x; o[5] = (_Float16)v1.y;
    o[6] = (_Float16)v1.z; o[7] = (_Float16)v1.w;
    *(half8*)&Ap[(size_t)r * KE + ph * 48 + j8 * 8] = o;
  }
}

// ---------------------------------------------------------------------------
// Kernel 3: class-grouped GEMM, m97 geometry: BM=BN=128, BK=64, 4 waves
// each 64x64 (4x4 frags) -> 8 ds_read_b128 : 16 MFMA per kf (was 6:8).
// global_load_lds(16B), XOR-swizzled LDS, 2-phase dbuf prefetch.
// ---------------------------------------------------------------------------
#define BM 128
#define BN 128

__global__ __launch_bounds__(256) void spt_gemm(
    const _Float16* __restrict__ Ap, const _Float16* __restrict__ Weff,
    const float* __restrict__ bias, float* __restrict__ out) {
  __shared__ _Float16 Al[2][BM * 64];     // 16 KB per buffer
  __shared__ _Float16 Bl[2][BN * 64];     // 16 KB per buffer

  const int t  = threadIdx.x;
  const int nt = blockIdx.x % 6;
  const int bt = blockIdx.x / 6;          // m-tile 0..99

  // class decode: tile counts {1,6,1,6,72,6,1,6,1}
  int cls, mt;
  if      (bt < 1)  { cls = 0; mt = bt; }
  else if (bt < 7)  { cls = 1; mt = bt - 1; }
  else if (bt < 8)  { cls = 2; mt = bt - 7; }
  else if (bt < 14) { cls = 3; mt = bt - 8; }
  else if (bt < 86) { cls = 4; mt = bt - 14; }
  else if (bt < 92) { cls = 5; mt = bt - 86; }
  else if (bt < 93) { cls = 6; mt = bt - 92; }
  else if (bt < 99) { cls = 7; mt = bt - 93; }
  else              { cls = 8; mt = bt - 99; }

  const int rh  = cls / 3, rw = cls % 3;
  const int per = ((rh == 1) ? 12 : 1) * ((rw == 1) ? 12 : 1);
  const int Mc  = NB * per;
  const int cbase   = cls_row_base(cls);
  const int rowbase = cbase + mt * BM;

  const int w = t >> 6, lane = t & 63;
  const int wr = w >> 1, wc = w & 1;
  const int lrow = lane & 15, lq = lane >> 4;

  // staging: chunk c = i*256+t -> row = i*32+(t>>3), 16B chunk j = t&7
  const int srow = t >> 3;
  const int js = (t & 7) ^ (srow & 7);    // pre-swizzled 16B-block index
  const _Float16* Agp[4];
  const _Float16* Bgp[4];
#pragma unroll
  for (int i = 0; i < 4; ++i) {
    int rA = rowbase + i * 32 + srow;
    int rmax = cbase + Mc - 1;            // clamp inside class (partial tiles)
    rA = (rA > rmax) ? rmax : rA;
    Agp[i] = Ap + (size_t)rA * KE + js * 8;
    Bgp[i] = Weff + ((size_t)cls * PD + nt * BN + i * 32 + srow) * KE + js * 8;
  }

  floatx4 acc[4][4];
#pragma unroll
  for (int m = 0; m < 4; ++m)
#pragma unroll
    for (int n = 0; n < 4; ++n) acc[m][n] = (floatx4)0.f;

#define STAGE(ks, sel)                                                        \
  {                                                                           \
    _Pragma("unroll")                                                         \
    for (int i = 0; i < 4; ++i)                                               \
      gl_lds16(Agp[i] + (ks) * 64, &Al[sel][i * 2048 + w * 512]);             \
    _Pragma("unroll")                                                         \
    for (int i = 0; i < 4; ++i)                                               \
      gl_lds16(Bgp[i] + (ks) * 64, &Bl[sel][i * 2048 + w * 512]);             \
  }

  int cur = 0;
  STAGE(0, 0);
  __syncthreads();
  for (int ks = 0; ks < 12; ++ks) {
    if (ks < 11) STAGE(ks + 1, cur ^ 1);
#pragma unroll
    for (int kf = 0; kf < 2; ++kf) {
      half8 af[4], bf[4];
#pragma unroll
      for (int m = 0; m < 4; ++m) {
        int row = wr * 64 + m * 16 + lrow;
        af[m] = *(const half8*)&Al[cur][row * 64
                 + ((kf * 32 + lq * 8) ^ ((row & 7) * 8))];
      }
#pragma unroll
      for (int n = 0; n < 4; ++n) {
        int row = wc * 64 + n * 16 + lrow;
        bf[n] = *(const half8*)&Bl[cur][row * 64
                 + ((kf * 32 + lq * 8) ^ ((row & 7) * 8))];
      }
#pragma unroll
      for (int m = 0; m < 4; ++m)
#pragma unroll
        for (int n = 0; n < 4; ++n)
          acc[m][n] = __builtin_amdgcn_mfma_f32_16x16x32_f16(
              af[m], bf[n], acc[m][n], 0, 0, 0);
    }
    __syncthreads();
    cur ^= 1;
  }

  // epilogue: bias + scatter class-grouped rows to (b, gh*14+gw)
  const int gh0 = (rh == 1) ? 1 : ((rh == 2) ? 13 : 0);
  const int gw0 = (rw == 1) ? 1 : ((rw == 2) ? 13 : 0);
  const int nw  = (rw == 1) ? 12 : 1;

  const int col = nt * BN + wc * 64 + lrow;
  float bv[4];
#pragma unroll
  for (int n = 0; n < 4; ++n) bv[n] = bias[col + n * 16];
  const int rq = lq * 4;
#pragma unroll
  for (int m = 0; m < 4; ++m) {
#pragma unroll
    for (int j = 0; j < 4; ++j) {
      int R = rowbase + wr * 64 + m * 16 + rq + j;
      int r = R - cbase;
      if (r < Mc) {
        int b, ih, iw;
        if (per == 1)        { b = r; ih = 0; iw = 0; }
        else if (per == 12)  { b = r / 12; int rm = r - b * 12;
                               ih = (nw == 1) ? rm : 0; iw = (nw == 1) ? 0 : rm; }
        else                 { b = r / 144; int rm = r - b * 144;
                               ih = rm / 12; iw = rm - ih * 12; }
        int p = (gh0 + ih) * 14 + (gw0 + iw);
        float* orow = out + ((size_t)b * 196 + p) * PD + col;
#pragma unroll
        for (int n = 0; n < 4; ++n) orow[n * 16] = acc[m][n][j] + bv[n];
      }
    }
  }
}

extern "C" void kernel_launch(void* const* d_in, const int* in_sizes, int n_in,
                              void* d_out, int out_size, void* d_ws, size_t ws_size,
                              hipStream_t stream) {
  const float* img  = (const float*)d_in[0];   // (64,224,224,3) fp32
  const float* W    = (const float*)d_in[1];   // (3840,768) fp32
  const float* bias = (const float*)d_in[2];   // (768,) fp32
  float* out = (float*)d_out;                  // (64,196,768) fp32
  _Float16* Weff = (_Float16*)d_ws;                          // 10,616,832 B
  _Float16* Ap   = (_Float16*)((char*)d_ws + 10616832);      // 19,267,584 B

  prep_weights<<<768, 256, 0, stream>>>(W, Weff);
  prep_imcol<<<2048, 256, 0, stream>>>(img, Ap);
  // 100 m-tiles (1+6+1+6+72+6+1+6+1) x 6 n-tiles
  spt_gemm<<<600, 256, 0, stream>>>(Ap, Weff, bias, out);
}

// Round 9
// 135.615 us; speedup vs baseline: 1.0541x; 1.0541x over previous
//
#include <hip/hip_runtime.h>
#include <hip/hip_bf16.h>

typedef _Float16 half8 __attribute__((ext_vector_type(8)));
typedef _Float16 half4 __attribute__((ext_vector_type(4)));
typedef float floatx4 __attribute__((ext_vector_type(4)));

#define PD 768   // projection dim (N)
#define KE 768   // effective K (16*16*3)
#define NB 64

// class row-bases (rows grouped by class; all class sizes are multiples of 64)
__device__ __forceinline__ int cls_row_base(int cls) {
  return (cls == 0) ? 0 : (cls == 1) ? 64 : (cls == 2) ? 832 : (cls == 3) ? 896
       : (cls == 4) ? 1664 : (cls == 5) ? 10880 : (cls == 6) ? 11648
       : (cls == 7) ? 11712 : 12480;
}

__device__ __forceinline__ void gl_lds16(const _Float16* g, _Float16* l) {
  __builtin_amdgcn_global_load_lds(
      (const __attribute__((address_space(1))) unsigned int*)g,
      (__attribute__((address_space(3))) unsigned int*)l, 16, 0, 0);
}

// ---------------------------------------------------------------------------
// Kernel 1 (MERGED): blocks [0,768) fold weights; blocks [768, 2816) im2col.
// Tests the per-dispatch-overhead hypothesis: 3 -> 2 dispatches.
// ---------------------------------------------------------------------------
__global__ __launch_bounds__(256) void prep_all(
    const float* __restrict__ W, const float* __restrict__ img,
    _Float16* __restrict__ Weff, _Float16* __restrict__ Ap) {
  __shared__ float Wl[60][68];      // weights path only (16.3 KB)
  const int t = threadIdx.x;

  if (blockIdx.x < 768) {
    // ---- prep_weights: 4 pixels (12 kk) x 64 d per block ----
    const int ck = blockIdx.x & 63;   // kk-chunk (12 kk = 4 pixels)
    const int cd = blockIdx.x >> 6;   // d-chunk (64)
    const int p0 = ck * 4;
    const int d0 = cd * 64;
    for (int c = t; c < 960; c += 256) {   // 60 rows * 16 float4
      int row = c >> 4, off = (c & 15) * 4;
      *(floatx4*)&Wl[row][off] =
          *(const floatx4*)&W[(size_t)(p0 * 15 + row) * PD + d0 + off];
    }
    __syncthreads();
    if (t < 192) {                    // 64 d x 3 kk-quads
      int d = t / 3, q = t - (t / 3) * 3;
      float vout[9][4];
#pragma unroll
      for (int s = 0; s < 4; ++s) {
        int kl = q * 4 + s;           // 0..11
        int pl = kl / 3, cc = kl - pl * 3;
        int pix = p0 + pl;
        int ph = pix >> 4, pw = pix & 15;
        int rb = pl * 15 + cc;
        float w0 = Wl[rb][d],     w1 = Wl[rb + 3][d], w2 = Wl[rb + 6][d],
              w3 = Wl[rb + 9][d], w4 = Wl[rb + 12][d];
        float hlt[3] = {1.f, 1.f, (ph < 8) ? 1.f : 0.f};
        float hge[3] = {(ph >= 8) ? 1.f : 0.f, 1.f, 1.f};
        float wlt[3] = {1.f, 1.f, (pw < 8) ? 1.f : 0.f};
        float wge[3] = {(pw >= 8) ? 1.f : 0.f, 1.f, 1.f};
#pragma unroll
        for (int rh = 0; rh < 3; ++rh)
#pragma unroll
          for (int rw = 0; rw < 3; ++rw)
            vout[rh * 3 + rw][s] = w0 + hlt[rh] * wlt[rw] * w1
                + hge[rh] * wlt[rw] * w2 + hlt[rh] * wge[rw] * w3
                + hge[rh] * wge[rw] * w4;
      }
#pragma unroll
      for (int cls = 0; cls < 9; ++cls) {
        half4 h;
        h.x = (_Float16)vout[cls][0]; h.y = (_Float16)vout[cls][1];
        h.z = (_Float16)vout[cls][2]; h.w = (_Float16)vout[cls][3];
        *(half4*)&Weff[((size_t)cls * PD + d0 + d) * KE + ck * 12 + q * 4] = h;
      }
    }
  } else {
    // ---- prep_imcol: A[12544][768] f16, rows class-grouped ----
    const int total = NB * 224 * 84;        // 1,204,224 8-float items
    for (int id = (blockIdx.x - 768) * 256 + t; id < total; id += 2048 * 256) {
      int b   = id / 18816;
      int rem = id - b * 18816;
      int h   = rem / 84;
      int c8  = rem - h * 84;
      int gw  = c8 / 6;
      int j8  = c8 - gw * 6;
      int gh  = h >> 4, ph = h & 15;
      int rh  = (gh == 0) ? 0 : ((gh >= 13) ? 2 : 1);
      int rw  = (gw == 0) ? 0 : ((gw >= 13) ? 2 : 1);
      int gh0 = (rh == 1) ? 1 : ((rh == 2) ? 13 : 0);
      int gw0 = (rw == 1) ? 1 : ((rw == 2) ? 13 : 0);
      int nh  = (rh == 1) ? 12 : 1;
      int nw  = (rw == 1) ? 12 : 1;
      int cls = rh * 3 + rw;
      int r   = cls_row_base(cls) + (b * nh + (gh - gh0)) * nw + (gw - gw0);
      const float* src = img + (size_t)(b * 224 + h) * 672 + c8 * 8;
      floatx4 v0 = *(const floatx4*)src;
      floatx4 v1 = *(const floatx4*)(src + 4);
      half8 o;
      o[0] = (_Float16)v0.x; o[1] = (_Float16)v0.y;
      o[2] = (_Float16)v0.z; o[3] = (_Float16)v0.w;
      o[4] = (_Float16)v1.x; o[5] = (_Float16)v1.y;
      o[6] = (_Float16)v1.z; o[7] = (_Float16)v1.w;
      *(half8*)&Ap[(size_t)r * KE + ph * 48 + j8 * 8] = o;
    }
  }
}

// ---------------------------------------------------------------------------
// Kernel 2: class-grouped GEMM, BM=BN=128, BK=64, 4 waves each 64x64,
// global_load_lds(16B), XOR-swizzled LDS, 2-phase dbuf prefetch,
// + XCD-aware chunked block swizzle (600 = 8 XCD x 75).
// ---------------------------------------------------------------------------
#define BM 128
#define BN 128

__global__ __launch_bounds__(256) void spt_gemm(
    const _Float16* __restrict__ Ap, const _Float16* __restrict__ Weff,
    const float* __restrict__ bias, float* __restrict__ out) {
  __shared__ _Float16 Al[2][BM * 64];     // 16 KB per buffer
  __shared__ _Float16 Bl[2][BN * 64];     // 16 KB per buffer

  const int t = threadIdx.x;
  // XCD swizzle: consecutive work-ids land on the same XCD (T1, bijective).
  const int wid = (blockIdx.x & 7) * 75 + (blockIdx.x >> 3);
  const int nt = wid % 6;
  const int bt = wid / 6;                 // m-tile 0..99

  // class decode: tile counts {1,6,1,6,72,6,1,6,1}
  int cls, mt;
  if      (bt < 1)  { cls = 0; mt = bt; }
  else if (bt < 7)  { cls = 1; mt = bt - 1; }
  else if (bt < 8)  { cls = 2; mt = bt - 7; }
  else if (bt < 14) { cls = 3; mt = bt - 8; }
  else if (bt < 86) { cls = 4; mt = bt - 14; }
  else if (bt < 92) { cls = 5; mt = bt - 86; }
  else if (bt < 93) { cls = 6; mt = bt - 92; }
  else if (bt < 99) { cls = 7; mt = bt - 93; }
  else              { cls = 8; mt = bt - 99; }

  const int rh  = cls / 3, rw = cls % 3;
  const int per = ((rh == 1) ? 12 : 1) * ((rw == 1) ? 12 : 1);
  const int Mc  = NB * per;
  const int cbase   = cls_row_base(cls);
  const int rowbase = cbase + mt * BM;

  const int w = t >> 6, lane = t & 63;
  const int wr = w >> 1, wc = w & 1;
  const int lrow = lane & 15, lq = lane >> 4;

  // staging: chunk c = i*256+t -> row = i*32+(t>>3), 16B chunk j = t&7
  const int srow = t >> 3;
  const int js = (t & 7) ^ (srow & 7);    // pre-swizzled 16B-block index
  const _Float16* Agp[4];
  const _Float16* Bgp[4];
#pragma unroll
  for (int i = 0; i < 4; ++i) {
    int rA = rowbase + i * 32 + srow;
    int rmax = cbase + Mc - 1;            // clamp inside class (partial tiles)
    rA = (rA > rmax) ? rmax : rA;
    Agp[i] = Ap + (size_t)rA * KE + js * 8;
    Bgp[i] = Weff + ((size_t)cls * PD + nt * BN + i * 32 + srow) * KE + js * 8;
  }

  floatx4 acc[4][4];
#pragma unroll
  for (int m = 0; m < 4; ++m)
#pragma unroll
    for (int n = 0; n < 4; ++n) acc[m][n] = (floatx4)0.f;

#define STAGE(ks, sel)                                                        \
  {                                                                           \
    _Pragma("unroll")                                                         \
    for (int i = 0; i < 4; ++i)                                               \
      gl_lds16(Agp[i] + (ks) * 64, &Al[sel][i * 2048 + w * 512]);             \
    _Pragma("unroll")                                                         \
    for (int i = 0; i < 4; ++i)                                               \
      gl_lds16(Bgp[i] + (ks) * 64, &Bl[sel][i * 2048 + w * 512]);             \
  }

  int cur = 0;
  STAGE(0, 0);
  __syncthreads();
  for (int ks = 0; ks < 12; ++ks) {
    if (ks < 11) STAGE(ks + 1, cur ^ 1);
#pragma unroll
    for (int kf = 0; kf < 2; ++kf) {
      half8 af[4], bf[4];
#pragma unroll
      for (int m = 0; m < 4; ++m) {
        int row = wr * 64 + m * 16 + lrow;
        af[m] = *(const half8*)&Al[cur][row * 64
                 + ((kf * 32 + lq * 8) ^ ((row & 7) * 8))];
      }
#pragma unroll
      for (int n = 0; n < 4; ++n) {
        int row = wc * 64 + n * 16 + lrow;
        bf[n] = *(const half8*)&Bl[cur][row * 64
                 + ((kf * 32 + lq * 8) ^ ((row & 7) * 8))];
      }
#pragma unroll
      for (int m = 0; m < 4; ++m)
#pragma unroll
        for (int n = 0; n < 4; ++n)
          acc[m][n] = __builtin_amdgcn_mfma_f32_16x16x32_f16(
              af[m], bf[n], acc[m][n], 0, 0, 0);
    }
    __syncthreads();
    cur ^= 1;
  }

  // epilogue: bias + scatter class-grouped rows to (b, gh*14+gw)
  const int gh0 = (rh == 1) ? 1 : ((rh == 2) ? 13 : 0);
  const int gw0 = (rw == 1) ? 1 : ((rw == 2) ? 13 : 0);
  const int nw  = (rw == 1) ? 12 : 1;

  const int col = nt * BN + wc * 64 + lrow;
  float bv[4];
#pragma unroll
  for (int n = 0; n < 4; ++n) bv[n] = bias[col + n * 16];
  const int rq = lq * 4;
#pragma unroll
  for (int m = 0; m < 4; ++m) {
#pragma unroll
    for (int j = 0; j < 4; ++j) {
      int R = rowbase + wr * 64 + m * 16 + rq + j;
      int r = R - cbase;
      if (r < Mc) {
        int b, ih, iw;
        if (per == 1)        { b = r; ih = 0; iw = 0; }
        else if (per == 12)  { b = r / 12; int rm = r - b * 12;
                               ih = (nw == 1) ? rm : 0; iw = (nw == 1) ? 0 : rm; }
        else                 { b = r / 144; int rm = r - b * 144;
                               ih = rm / 12; iw = rm - ih * 12; }
        int p = (gh0 + ih) * 14 + (gw0 + iw);
        float* orow = out + ((size_t)b * 196 + p) * PD + col;
#pragma unroll
        for (int n = 0; n < 4; ++n) orow[n * 16] = acc[m][n][j] + bv[n];
      }
    }
  }
}

extern "C" void kernel_launch(void* const* d_in, const int* in_sizes, int n_in,
                              void* d_out, int out_size, void* d_ws, size_t ws_size,
                              hipStream_t stream) {
  const float* img  = (const float*)d_in[0];   // (64,224,224,3) fp32
  const float* W    = (const float*)d_in[1];   // (3840,768) fp32
  const float* bias = (const float*)d_in[2];   // (768,) fp32
  float* out = (float*)d_out;                  // (64,196,768) fp32
  _Float16* Weff = (_Float16*)d_ws;                          // 10,616,832 B
  _Float16* Ap   = (_Float16*)((char*)d_ws + 10616832);      // 19,267,584 B

  prep_all<<<2816, 256, 0, stream>>>(W, img, Weff, Ap);
  // 100 m-tiles (1+6+1+6+72+6+1+6+1) x 6 n-tiles, XCD-swizzled
  spt_gemm<<<600, 256, 0, stream>>>(Ap, Weff, bias, out);
}